// Round 7
// baseline (400.259 us; speedup 1.0000x reference)
//
#include <hip/hip_runtime.h>

#define NN 200

typedef short s8v __attribute__((ext_vector_type(8)));   // 8 bf16 in 4 VGPRs
typedef float f4v __attribute__((ext_vector_type(4)));   // MFMA accum

__device__ __forceinline__ unsigned short f2bf(float f) {
    unsigned u = __float_as_uint(f);
    u += 0x7fffu + ((u >> 16) & 1u);   // RNE
    return (unsigned short)(u >> 16);
}

// ---------------- prep ----------------
__global__ __launch_bounds__(256) void k_sums(const float* __restrict__ adj,
                                              float* __restrict__ cs, float* __restrict__ rs) {
    int t = blockIdx.x;
    int tid = threadIdx.x;
    float c = 0.f, r = 0.f;
    for (int p = tid; p < NN; p += 256) {
        if (p != t) {
            c += adj[p * NN + t];
            r += adj[t * NN + p];
        }
    }
    #pragma unroll
    for (int off = 32; off; off >>= 1) {
        c += __shfl_down(c, off);
        r += __shfl_down(r, off);
    }
    __shared__ float sc[4], sr[4];
    if ((tid & 63) == 0) { sc[tid >> 6] = c; sr[tid >> 6] = r; }
    __syncthreads();
    if (tid == 0) {
        cs[t] = sc[0] + sc[1] + sc[2] + sc[3];
        rs[t] = sr[0] + sr[1] + sr[2] + sr[3];
    }
}

// L fp32 [200][200]; Lh bf16 [224][224] (row j, col e, zero-padded);
// LTh bf16 [256][224] (row i, col b = L[b][i], zero-padded)
__global__ __launch_bounds__(256) void k_lap2(const float* __restrict__ adj,
    const float* __restrict__ cs, const float* __restrict__ rs,
    float* __restrict__ L, unsigned short* __restrict__ Lh, unsigned short* __restrict__ LTh) {
    int idx = blockIdx.x * 256 + threadIdx.x;
    int p = idx >> 8, q = idx & 255;          // p in [0,224), q in [0,256)
    if (p >= 224) return;
    float v = 0.f;
    if (p < NN && q < NN) {
        float a = (p == q) ? 0.f : adj[p * NN + q];
        float d0 = (cs[p] > 0.f) ? rsqrtf(cs[p]) : 0.f;
        float d1 = (rs[q] > 0.f) ? rsqrtf(rs[q]) : 0.f;
        v = d0 * a * d1;
        L[p * NN + q] = v;
    }
    unsigned short h = f2bf(v);
    if (q < 224) Lh[p * 224 + q] = h;
    LTh[q * 224 + p] = h;
}

// C2 = 2*L*L - I ; C2h [224][224], C2Th [256][224] zero-padded
__global__ __launch_bounds__(256) void k_sq2(const float* __restrict__ L,
    unsigned short* __restrict__ C2h, unsigned short* __restrict__ C2Th) {
    int idx = blockIdx.x * 256 + threadIdx.x;
    int p = idx >> 8, q = idx & 255;
    if (p >= 224) return;
    float v = 0.f;
    if (p < NN && q < NN) {
        float s = 0.f;
        for (int r2 = 0; r2 < NN; ++r2) s += L[p * NN + r2] * L[r2 * NN + q];
        v = 2.f * s - ((p == q) ? 1.f : 0.f);
    }
    unsigned short h = f2bf(v);
    if (q < 224) C2h[p * 224 + q] = h;
    C2Th[q * 224 + p] = h;
}

// WmT bf16 [192 n][96 k], n = k2*64+o, k = k1*32+c  ([n][k]-major for B-frags)
__global__ __launch_bounds__(256) void k_wprep2(const float* __restrict__ w,
    unsigned short* __restrict__ WmT) {
    int idx = blockIdx.x * 256 + threadIdx.x;
    if (idx < 192 * 96) {
        int n = idx / 96, k = idx - n * 96;
        int k1 = k >> 5, c = k & 31;
        int k2 = n >> 6, o = n & 63;
        WmT[idx] = f2bf(w[o * 288 + (k1 * 3 + k2) * 32 + c]);
    }
}

// ---------------- cast: X -> Xh bf16 [a][b][6400], XhT bf16 [a][6400][224] (b padded 0) --
__global__ __launch_bounds__(256) void k_cast(const float* __restrict__ x,
    unsigned short* __restrict__ Xh, unsigned short* __restrict__ XhT, int a0) {
    int a = blockIdx.z;
    int b0 = blockIdx.y * 32;
    int jc0 = blockIdx.x * 64;
    int tid = threadIdx.x;
    __shared__ unsigned short Xs[32][65];
    const float* xb = x + (size_t)(a0 + a) * (NN * 6400);
    int r = tid >> 6, q = tid & 63;
    #pragma unroll
    for (int k = 0; k < 8; ++k) {
        int rr = r + k * 4;
        int b = b0 + rr;
        float v = (b < NN) ? xb[(size_t)b * 6400 + jc0 + q] : 0.f;
        unsigned short h = f2bf(v);
        Xs[rr][q] = h;
        if (b < NN) Xh[((size_t)a * NN + b) * 6400 + jc0 + q] = h;
    }
    __syncthreads();
    int jcl = tid >> 2, bs = (tid & 3) * 8;
    s8v v;
    #pragma unroll
    for (int j2 = 0; j2 < 8; ++j2) v[j2] = (short)Xs[bs + j2][jcl];
    *(s8v*)(XhT + (size_t)a * (6400 * 224) + (size_t)(jc0 + jcl) * 224 + b0 + bs) = v;
}

// ---------------- stage 1: Y1[i][jc] = sum_b L[b][i] X[b][jc]; Y2 with C2. MFMA. --------
__global__ __launch_bounds__(256) void k_y(
    const unsigned short* __restrict__ LTh, const unsigned short* __restrict__ C2Th,
    const unsigned short* __restrict__ XhT,
    unsigned short* __restrict__ Y1, unsigned short* __restrict__ Y2, int i0, int Gi) {
    int a = blockIdx.z;
    int itile = blockIdx.y;
    int jc0 = blockIdx.x << 8;
    int tid = threadIdx.x;
    int w = tid >> 6, l15 = tid & 15, g = (tid & 63) >> 4;

    __shared__ unsigned short As[2][32][40];   // 80B rows: 16B-aligned b128 frags
    __shared__ unsigned short Xt[256][40];     // [jc][b]  ([n][k]-major)

    const unsigned short* xtb = XhT + (size_t)a * (6400 * 224) + (size_t)jc0 * 224;
    int ibase = i0 + itile * 32;

    f4v z = {0.f, 0.f, 0.f, 0.f};
    f4v acc[2][2][4];
    #pragma unroll
    for (int m = 0; m < 2; ++m)
        #pragma unroll
        for (int f = 0; f < 2; ++f)
            #pragma unroll
            for (int n = 0; n < 4; ++n) acc[m][f][n] = z;

    int amat = tid >> 7, arr = (tid >> 2) & 31, ah = tid & 3;
    const unsigned short* asrc = (amat ? C2Th : LTh) + (size_t)(ibase + arr) * 224 + ah * 8;

    for (int ks = 0; ks < 7; ++ks) {
        int b0 = ks * 32;
        __syncthreads();
        *(s8v*)&As[amat][arr][ah * 8] = *(const s8v*)(asrc + b0);
        const unsigned short* xs = xtb + (size_t)tid * 224 + b0;
        #pragma unroll
        for (int h = 0; h < 4; ++h)
            *(s8v*)&Xt[tid][h * 8] = *(const s8v*)(xs + h * 8);
        __syncthreads();

        s8v bfr[4];
        #pragma unroll
        for (int nf = 0; nf < 4; ++nf)
            bfr[nf] = *(s8v*)&Xt[w * 64 + nf * 16 + l15][g * 8];
        #pragma unroll
        for (int m = 0; m < 2; ++m) {
            #pragma unroll
            for (int f = 0; f < 2; ++f) {
                s8v af = *(s8v*)&As[m][f * 16 + l15][g * 8];
                #pragma unroll
                for (int nf = 0; nf < 4; ++nf)
                    acc[m][f][nf] = __builtin_amdgcn_mfma_f32_16x16x32_bf16(
                        af, bfr[nf], acc[m][f][nf], 0, 0, 0);
            }
        }
    }

    #pragma unroll
    for (int f = 0; f < 2; ++f) {
        #pragma unroll
        for (int r = 0; r < 4; ++r) {
            int il_ = itile * 32 + f * 16 + 4 * g + r;
            if (il_ < Gi && i0 + il_ < NN) {
                size_t base = ((size_t)a * Gi + il_) * 6400 + jc0 + w * 64 + l15;
                #pragma unroll
                for (int nf = 0; nf < 4; ++nf) {
                    Y1[base + nf * 16] = f2bf(acc[0][f][nf][r]);
                    Y2[base + nf * 16] = f2bf(acc[1][f][nf][r]);
                }
            }
        }
    }
}

// ---------------- fused stages 2+3: one block per t row, 256 threads / 4 waves.
// Phase A: U=[X|Y1|Y2][j][96] x WmT -> D (regs, accD) + E1/E2 (LDS [e/8][o][e%8], e<200)
// Phase B: out[j][o] = accD + L[j][e]*E1[e][o] + C2[j][e]*E2[e][o] + bias
// LDS = 51200 B -> 3 blocks/CU = 3 waves/SIMD; VGPR cap 170 via launch_bounds(256,3).
__global__ __launch_bounds__(256, 3) void k_fused(
    const unsigned short* __restrict__ Xh, const unsigned short* __restrict__ Y1,
    const unsigned short* __restrict__ Y2, const unsigned short* __restrict__ WmT,
    const unsigned short* __restrict__ Lh, const unsigned short* __restrict__ C2h,
    const float* __restrict__ bias, float* __restrict__ out,
    int a0, int i0, int Gi) {
    int tl = blockIdx.x;
    int al = tl / Gi, il = tl - al * Gi;
    int tid = threadIdx.x;
    int w = tid >> 6, l15 = tid & 15, g = (tid & 63) >> 4;

    // E LDS: [tensor][e/8][o][e%8], e < 200 (25 subtiles); read bank = (4*l15+d)%32 -> 2-way
    __shared__ unsigned short EL[2][25][64][8];   // 51200 B

    const unsigned short* xrow = Xh + (size_t)(al * NN + i0 + il) * 6400;
    const unsigned short* y1r = Y1 + (size_t)tl * 6400;
    const unsigned short* y2r = Y2 + (size_t)tl * 6400;

    f4v z = {0.f, 0.f, 0.f, 0.f};
    f4v accD[2][2][4];
    #pragma unroll
    for (int jh = 0; jh < 2; ++jh)
        #pragma unroll
        for (int f = 0; f < 2; ++f)
            #pragma unroll
            for (int n = 0; n < 4; ++n) accD[jh][f][n] = z;

    // ---------- phase A ----------
    #pragma unroll
    for (int jh = 0; jh < 2; ++jh) {
        int jrow0 = jh * 128 + w * 32;
        s8v afr[3][2];
        #pragma unroll
        for (int f = 0; f < 2; ++f) {
            int j = jrow0 + f * 16 + l15;
            int jc = j < NN ? j : NN - 1;
            afr[0][f] = *(const s8v*)(xrow + jc * 32 + g * 8);
            afr[1][f] = *(const s8v*)(y1r + jc * 32 + g * 8);
            afr[2][f] = *(const s8v*)(y2r + jc * 32 + g * 8);
        }

        f4v accE[2][8];
        #pragma unroll
        for (int f = 0; f < 2; ++f)
            #pragma unroll
            for (int n = 0; n < 8; ++n) accE[f][n] = z;

        #pragma unroll
        for (int s = 0; s < 3; ++s) {
            #pragma unroll
            for (int nf = 0; nf < 12; ++nf) {
                s8v bf = *(const s8v*)(WmT + (nf * 16 + l15) * 96 + s * 32 + g * 8);
                #pragma unroll
                for (int f = 0; f < 2; ++f) {
                    if (nf < 4)
                        accD[jh][f][nf] = __builtin_amdgcn_mfma_f32_16x16x32_bf16(
                            afr[s][f], bf, accD[jh][f][nf], 0, 0, 0);
                    else
                        accE[f][nf - 4] = __builtin_amdgcn_mfma_f32_16x16x32_bf16(
                            afr[s][f], bf, accE[f][nf - 4], 0, 0, 0);
                }
            }
        }

        // write E fragments to LDS (only e < NN exists; NN even, r0 even => e+1 < NN too)
        #pragma unroll
        for (int f = 0; f < 2; ++f) {
            int ebase = jrow0 + f * 16;
            #pragma unroll
            for (int nf = 0; nf < 8; ++nf) {
                int tns = nf >> 2;
                int o = (nf & 3) * 16 + l15;
                #pragma unroll
                for (int r0 = 0; r0 < 4; r0 += 2) {
                    int e = ebase + 4 * g + r0;
                    if (e < NN) {
                        unsigned short u0 = f2bf(accE[f][nf][r0]);
                        unsigned short u1 = f2bf(accE[f][nf][r0 + 1]);
                        unsigned pk = (unsigned)u0 | ((unsigned)u1 << 16);
                        *(unsigned*)&EL[tns][e >> 3][o][e & 7] = pk;
                    }
                }
            }
        }
    }

    __syncthreads();

    // ---------- phase B ----------
    #pragma unroll
    for (int ks = 0; ks < 7; ++ks) {
        int eb = 4 * ks + g;
        s8v b1[4], b2[4];
        if (eb < 25) {
            #pragma unroll
            for (int nf = 0; nf < 4; ++nf) {
                b1[nf] = *(const s8v*)&EL[0][eb][nf * 16 + l15][0];
                b2[nf] = *(const s8v*)&EL[1][eb][nf * 16 + l15][0];
            }
        } else {
            s8v zv = {0, 0, 0, 0, 0, 0, 0, 0};
            #pragma unroll
            for (int nf = 0; nf < 4; ++nf) { b1[nf] = zv; b2[nf] = zv; }
        }
        #pragma unroll
        for (int jh = 0; jh < 2; ++jh) {
            #pragma unroll
            for (int r2 = 0; r2 < 2; ++r2) {
                int jb = jh * 128 + w * 32 + r2 * 16;
                if (jb < NN) {
                    int aoff = (jb + l15) * 224 + ks * 32 + g * 8;
                    s8v a1 = *(const s8v*)(Lh + aoff);
                    s8v a2 = *(const s8v*)(C2h + aoff);
                    #pragma unroll
                    for (int nf = 0; nf < 4; ++nf) {
                        accD[jh][r2][nf] = __builtin_amdgcn_mfma_f32_16x16x32_bf16(
                            a1, b1[nf], accD[jh][r2][nf], 0, 0, 0);
                        accD[jh][r2][nf] = __builtin_amdgcn_mfma_f32_16x16x32_bf16(
                            a2, b2[nf], accD[jh][r2][nf], 0, 0, 0);
                    }
                }
            }
        }
    }

    // ---------- epilogue ----------
    float bv[4];
    #pragma unroll
    for (int nf = 0; nf < 4; ++nf) bv[nf] = bias[nf * 16 + l15];
    float* ob = out + ((size_t)(a0 + al) * NN + (i0 + il)) * 12800;
    #pragma unroll
    for (int jh = 0; jh < 2; ++jh) {
        #pragma unroll
        for (int r2 = 0; r2 < 2; ++r2) {
            int jb = jh * 128 + w * 32 + r2 * 16;
            if (jb < NN) {
                #pragma unroll
                for (int r = 0; r < 4; ++r) {
                    int j = jb + 4 * g + r;
                    if (j < NN) {
                        #pragma unroll
                        for (int nf = 0; nf < 4; ++nf)
                            ob[(size_t)j * 64 + nf * 16 + l15] = accD[jh][r2][nf][r] + bv[nf];
                    }
                }
            }
        }
    }
}

extern "C" void kernel_launch(void* const* d_in, const int* in_sizes, int n_in,
                              void* d_out, int out_size, void* d_ws, size_t ws_size,
                              hipStream_t stream) {
    const float* x    = (const float*)d_in[0];   // [8,200,200,32] fp32
    const float* adj  = (const float*)d_in[1];   // [200,200] fp32
    const float* w    = (const float*)d_in[2];   // [64,288] fp32
    const float* bias = (const float*)d_in[3];   // [64] fp32
    float* out = (float*)d_out;                  // [8,200,200,64] fp32

    char* ws = (char*)d_ws;
    size_t off = 0;
    auto alloc = [&](size_t bytes) { size_t p = off; off = (off + bytes + 255) & ~(size_t)255; return p; };
    float* cs = (float*)(ws + alloc(NN * 4));
    float* rs = (float*)(ws + alloc(NN * 4));
    float* L  = (float*)(ws + alloc(NN * NN * 4));
    unsigned short* Lh   = (unsigned short*)(ws + alloc(224 * 224 * 2));
    unsigned short* C2h  = (unsigned short*)(ws + alloc(224 * 224 * 2));
    unsigned short* LTh  = (unsigned short*)(ws + alloc(256 * 224 * 2));
    unsigned short* C2Th = (unsigned short*)(ws + alloc(256 * 224 * 2));
    unsigned short* WmT  = (unsigned short*)(ws + alloc(192 * 96 * 2));
    size_t fixedEnd = off;

    // chunking over (a, i): per-a Xh+XhT, per-(a,i)-row Y1/Y2
    const int cfgA[8] = {8, 8, 8, 8, 4, 2, 1, 1};
    const int cfgG[8] = {200, 100, 50, 25, 25, 25, 25, 5};
    size_t perA = (size_t)NN * 6400 * 2 + (size_t)6400 * 224 * 2;
    size_t perR = (size_t)2 * 6400 * 2;   // Y1+Y2 bytes per t row
    int Ab = 1, Gi = 5;
    for (int k = 0; k < 8; ++k) {
        size_t R_ = (size_t)cfgA[k] * cfgG[k];
        size_t need = fixedEnd + (size_t)cfgA[k] * perA + R_ * perR + 8192;
        if (need <= ws_size) { Ab = cfgA[k]; Gi = cfgG[k]; break; }
    }
    int R = Ab * Gi;
    unsigned short* Xh  = (unsigned short*)(ws + alloc((size_t)Ab * NN * 6400 * 2));
    unsigned short* XhT = (unsigned short*)(ws + alloc((size_t)Ab * 6400 * 224 * 2));
    unsigned short* Y1  = (unsigned short*)(ws + alloc((size_t)R * 6400 * 2));
    unsigned short* Y2  = (unsigned short*)(ws + alloc((size_t)R * 6400 * 2));

    k_sums<<<dim3(NN), dim3(256), 0, stream>>>(adj, cs, rs);
    k_lap2<<<dim3(224), dim3(256), 0, stream>>>(adj, cs, rs, L, Lh, LTh);
    k_sq2<<<dim3(224), dim3(256), 0, stream>>>(L, C2h, C2Th);
    k_wprep2<<<dim3(72), dim3(256), 0, stream>>>(w, WmT);

    int nIT = (Gi + 31) / 32;
    for (int a0 = 0; a0 < 8; a0 += Ab) {
        k_cast<<<dim3(100, 7, Ab), dim3(256), 0, stream>>>(x, Xh, XhT, a0);
        for (int i0 = 0; i0 < NN; i0 += Gi) {
            k_y<<<dim3(25, nIT, Ab), dim3(256), 0, stream>>>(LTh, C2Th, XhT, Y1, Y2, i0, Gi);
            k_fused<<<dim3(R), dim3(256), 0, stream>>>(Xh, Y1, Y2, WmT, Lh, C2h, bias, out, a0, i0, Gi);
        }
    }
}

// Round 8
// 302.685 us; speedup vs baseline: 1.3224x; 1.3224x over previous
//
#include <hip/hip_runtime.h>

#define NN 200

typedef short s8v __attribute__((ext_vector_type(8)));   // 8 bf16 in 4 VGPRs
typedef float f4v __attribute__((ext_vector_type(4)));   // MFMA accum

__device__ __forceinline__ unsigned short f2bf(float f) {
    unsigned u = __float_as_uint(f);
    u += 0x7fffu + ((u >> 16) & 1u);   // RNE
    return (unsigned short)(u >> 16);
}

// ---------------- prep ----------------
__global__ __launch_bounds__(256) void k_sums(const float* __restrict__ adj,
                                              float* __restrict__ cs, float* __restrict__ rs) {
    int t = blockIdx.x;
    int tid = threadIdx.x;
    float c = 0.f, r = 0.f;
    for (int p = tid; p < NN; p += 256) {
        if (p != t) {
            c += adj[p * NN + t];
            r += adj[t * NN + p];
        }
    }
    #pragma unroll
    for (int off = 32; off; off >>= 1) {
        c += __shfl_down(c, off);
        r += __shfl_down(r, off);
    }
    __shared__ float sc[4], sr[4];
    if ((tid & 63) == 0) { sc[tid >> 6] = c; sr[tid >> 6] = r; }
    __syncthreads();
    if (tid == 0) {
        cs[t] = sc[0] + sc[1] + sc[2] + sc[3];
        rs[t] = sr[0] + sr[1] + sr[2] + sr[3];
    }
}

// L fp32 [200][200]; Lh bf16 [224][224] (row j, col e, zero-padded);
// LTh bf16 [256][224] (row i, col b = L[b][i], zero-padded)
__global__ __launch_bounds__(256) void k_lap2(const float* __restrict__ adj,
    const float* __restrict__ cs, const float* __restrict__ rs,
    float* __restrict__ L, unsigned short* __restrict__ Lh, unsigned short* __restrict__ LTh) {
    int idx = blockIdx.x * 256 + threadIdx.x;
    int p = idx >> 8, q = idx & 255;          // p in [0,224), q in [0,256)
    if (p >= 224) return;
    float v = 0.f;
    if (p < NN && q < NN) {
        float a = (p == q) ? 0.f : adj[p * NN + q];
        float d0 = (cs[p] > 0.f) ? rsqrtf(cs[p]) : 0.f;
        float d1 = (rs[q] > 0.f) ? rsqrtf(rs[q]) : 0.f;
        v = d0 * a * d1;
        L[p * NN + q] = v;
    }
    unsigned short h = f2bf(v);
    if (q < 224) Lh[p * 224 + q] = h;
    LTh[q * 224 + p] = h;
}

// C2 = 2*L*L - I ; C2h [224][224], C2Th [256][224] zero-padded
__global__ __launch_bounds__(256) void k_sq2(const float* __restrict__ L,
    unsigned short* __restrict__ C2h, unsigned short* __restrict__ C2Th) {
    int idx = blockIdx.x * 256 + threadIdx.x;
    int p = idx >> 8, q = idx & 255;
    if (p >= 224) return;
    float v = 0.f;
    if (p < NN && q < NN) {
        float s = 0.f;
        for (int r2 = 0; r2 < NN; ++r2) s += L[p * NN + r2] * L[r2 * NN + q];
        v = 2.f * s - ((p == q) ? 1.f : 0.f);
    }
    unsigned short h = f2bf(v);
    if (q < 224) C2h[p * 224 + q] = h;
    C2Th[q * 224 + p] = h;
}

// WmT bf16 [192 n][96 k], n = k2*64+o, k = k1*32+c  ([n][k]-major for B-frags)
__global__ __launch_bounds__(256) void k_wprep2(const float* __restrict__ w,
    unsigned short* __restrict__ WmT) {
    int idx = blockIdx.x * 256 + threadIdx.x;
    if (idx < 192 * 96) {
        int n = idx / 96, k = idx - n * 96;
        int k1 = k >> 5, c = k & 31;
        int k2 = n >> 6, o = n & 63;
        WmT[idx] = f2bf(w[o * 288 + (k1 * 3 + k2) * 32 + c]);
    }
}

// ---------------- cast: X -> Xh bf16 [a][b][6400], XhT bf16 [a][6400][224] (b padded 0) --
__global__ __launch_bounds__(256) void k_cast(const float* __restrict__ x,
    unsigned short* __restrict__ Xh, unsigned short* __restrict__ XhT, int a0) {
    int a = blockIdx.z;
    int b0 = blockIdx.y * 32;
    int jc0 = blockIdx.x * 64;
    int tid = threadIdx.x;
    __shared__ unsigned short Xs[32][65];
    const float* xb = x + (size_t)(a0 + a) * (NN * 6400);
    int r = tid >> 6, q = tid & 63;
    #pragma unroll
    for (int k = 0; k < 8; ++k) {
        int rr = r + k * 4;
        int b = b0 + rr;
        float v = (b < NN) ? xb[(size_t)b * 6400 + jc0 + q] : 0.f;
        unsigned short h = f2bf(v);
        Xs[rr][q] = h;
        if (b < NN) Xh[((size_t)a * NN + b) * 6400 + jc0 + q] = h;
    }
    __syncthreads();
    int jcl = tid >> 2, bs = (tid & 3) * 8;
    s8v v;
    #pragma unroll
    for (int j2 = 0; j2 < 8; ++j2) v[j2] = (short)Xs[bs + j2][jcl];
    *(s8v*)(XhT + (size_t)a * (6400 * 224) + (size_t)(jc0 + jcl) * 224 + b0 + bs) = v;
}

// ---------------- stage 1: Y1[i][jc] = sum_b L[b][i] X[b][jc]; Y2 with C2. MFMA. --------
__global__ __launch_bounds__(256) void k_y(
    const unsigned short* __restrict__ LTh, const unsigned short* __restrict__ C2Th,
    const unsigned short* __restrict__ XhT,
    unsigned short* __restrict__ Y1, unsigned short* __restrict__ Y2, int i0, int Gi) {
    int a = blockIdx.z;
    int itile = blockIdx.y;
    int jc0 = blockIdx.x << 8;
    int tid = threadIdx.x;
    int w = tid >> 6, l15 = tid & 15, g = (tid & 63) >> 4;

    __shared__ unsigned short As[2][32][40];   // 80B rows: 16B-aligned b128 frags
    __shared__ unsigned short Xt[256][40];     // [jc][b]  ([n][k]-major)

    const unsigned short* xtb = XhT + (size_t)a * (6400 * 224) + (size_t)jc0 * 224;
    int ibase = i0 + itile * 32;

    f4v z = {0.f, 0.f, 0.f, 0.f};
    f4v acc[2][2][4];
    #pragma unroll
    for (int m = 0; m < 2; ++m)
        #pragma unroll
        for (int f = 0; f < 2; ++f)
            #pragma unroll
            for (int n = 0; n < 4; ++n) acc[m][f][n] = z;

    int amat = tid >> 7, arr = (tid >> 2) & 31, ah = tid & 3;
    const unsigned short* asrc = (amat ? C2Th : LTh) + (size_t)(ibase + arr) * 224 + ah * 8;

    for (int ks = 0; ks < 7; ++ks) {
        int b0 = ks * 32;
        __syncthreads();
        *(s8v*)&As[amat][arr][ah * 8] = *(const s8v*)(asrc + b0);
        const unsigned short* xs = xtb + (size_t)tid * 224 + b0;
        #pragma unroll
        for (int h = 0; h < 4; ++h)
            *(s8v*)&Xt[tid][h * 8] = *(const s8v*)(xs + h * 8);
        __syncthreads();

        s8v bfr[4];
        #pragma unroll
        for (int nf = 0; nf < 4; ++nf)
            bfr[nf] = *(s8v*)&Xt[w * 64 + nf * 16 + l15][g * 8];
        #pragma unroll
        for (int m = 0; m < 2; ++m) {
            #pragma unroll
            for (int f = 0; f < 2; ++f) {
                s8v af = *(s8v*)&As[m][f * 16 + l15][g * 8];
                #pragma unroll
                for (int nf = 0; nf < 4; ++nf)
                    acc[m][f][nf] = __builtin_amdgcn_mfma_f32_16x16x32_bf16(
                        af, bfr[nf], acc[m][f][nf], 0, 0, 0);
            }
        }
    }

    #pragma unroll
    for (int f = 0; f < 2; ++f) {
        #pragma unroll
        for (int r = 0; r < 4; ++r) {
            int il_ = itile * 32 + f * 16 + 4 * g + r;
            if (il_ < Gi && i0 + il_ < NN) {
                size_t base = ((size_t)a * Gi + il_) * 6400 + jc0 + w * 64 + l15;
                #pragma unroll
                for (int nf = 0; nf < 4; ++nf) {
                    Y1[base + nf * 16] = f2bf(acc[0][f][nf][r]);
                    Y2[base + nf * 16] = f2bf(acc[1][f][nf][r]);
                }
            }
        }
    }
}

// ---------------- fused stages 2+3: one block per t row, 256 threads / 4 waves.
// Phase A: U=[X|Y1|Y2][j][96] x WmT -> D (regs, accD) + E1/E2 (LDS [e/8][o][e%8], e<200)
// Phase B: out[j][o] = accD + L[j][e]*E1[e][o] + C2[j][e]*E2[e][o] + bias
// LDS = 51200 B -> 3 blocks/CU; NO min-waves bound (forcing it spills: r6/r7 post-mortem).
__global__ __launch_bounds__(256) void k_fused(
    const unsigned short* __restrict__ Xh, const unsigned short* __restrict__ Y1,
    const unsigned short* __restrict__ Y2, const unsigned short* __restrict__ WmT,
    const unsigned short* __restrict__ Lh, const unsigned short* __restrict__ C2h,
    const float* __restrict__ bias, float* __restrict__ out,
    int a0, int i0, int Gi) {
    int tl = blockIdx.x;
    int al = tl / Gi, il = tl - al * Gi;
    int tid = threadIdx.x;
    int w = tid >> 6, l15 = tid & 15, g = (tid & 63) >> 4;

    // E LDS: [tensor][e/8][o][e%8], e < 200 (25 subtiles); read bank = (4*l15+d)%32 -> 2-way
    __shared__ unsigned short EL[2][25][64][8];   // 51200 B

    const unsigned short* xrow = Xh + (size_t)(al * NN + i0 + il) * 6400;
    const unsigned short* y1r = Y1 + (size_t)tl * 6400;
    const unsigned short* y2r = Y2 + (size_t)tl * 6400;

    f4v z = {0.f, 0.f, 0.f, 0.f};
    f4v accD[2][2][4];
    #pragma unroll
    for (int jh = 0; jh < 2; ++jh)
        #pragma unroll
        for (int f = 0; f < 2; ++f)
            #pragma unroll
            for (int n = 0; n < 4; ++n) accD[jh][f][n] = z;

    // ---------- phase A ----------
    #pragma unroll
    for (int jh = 0; jh < 2; ++jh) {
        int jrow0 = jh * 128 + w * 32;
        s8v afr[3][2];
        #pragma unroll
        for (int f = 0; f < 2; ++f) {
            int j = jrow0 + f * 16 + l15;
            int jc = j < NN ? j : NN - 1;
            afr[0][f] = *(const s8v*)(xrow + jc * 32 + g * 8);
            afr[1][f] = *(const s8v*)(y1r + jc * 32 + g * 8);
            afr[2][f] = *(const s8v*)(y2r + jc * 32 + g * 8);
        }

        f4v accE[2][8];
        #pragma unroll
        for (int f = 0; f < 2; ++f)
            #pragma unroll
            for (int n = 0; n < 8; ++n) accE[f][n] = z;

        #pragma unroll
        for (int s = 0; s < 3; ++s) {
            #pragma unroll
            for (int nf = 0; nf < 12; ++nf) {
                s8v bf = *(const s8v*)(WmT + (nf * 16 + l15) * 96 + s * 32 + g * 8);
                #pragma unroll
                for (int f = 0; f < 2; ++f) {
                    if (nf < 4)
                        accD[jh][f][nf] = __builtin_amdgcn_mfma_f32_16x16x32_bf16(
                            afr[s][f], bf, accD[jh][f][nf], 0, 0, 0);
                    else
                        accE[f][nf - 4] = __builtin_amdgcn_mfma_f32_16x16x32_bf16(
                            afr[s][f], bf, accE[f][nf - 4], 0, 0, 0);
                }
            }
        }

        // write E fragments to LDS (only e < NN exists; NN even, r0 even => e+1 < NN too)
        #pragma unroll
        for (int f = 0; f < 2; ++f) {
            int ebase = jrow0 + f * 16;
            #pragma unroll
            for (int nf = 0; nf < 8; ++nf) {
                int tns = nf >> 2;
                int o = (nf & 3) * 16 + l15;
                #pragma unroll
                for (int r0 = 0; r0 < 4; r0 += 2) {
                    int e = ebase + 4 * g + r0;
                    if (e < NN) {
                        unsigned short u0 = f2bf(accE[f][nf][r0]);
                        unsigned short u1 = f2bf(accE[f][nf][r0 + 1]);
                        unsigned pk = (unsigned)u0 | ((unsigned)u1 << 16);
                        *(unsigned*)&EL[tns][e >> 3][o][e & 7] = pk;
                    }
                }
            }
        }
    }

    __syncthreads();

    // ---------- phase B ----------
    #pragma unroll
    for (int ks = 0; ks < 7; ++ks) {
        int eb = 4 * ks + g;
        s8v b1[4], b2[4];
        if (eb < 25) {
            #pragma unroll
            for (int nf = 0; nf < 4; ++nf) {
                b1[nf] = *(const s8v*)&EL[0][eb][nf * 16 + l15][0];
                b2[nf] = *(const s8v*)&EL[1][eb][nf * 16 + l15][0];
            }
        } else {
            s8v zv = {0, 0, 0, 0, 0, 0, 0, 0};
            #pragma unroll
            for (int nf = 0; nf < 4; ++nf) { b1[nf] = zv; b2[nf] = zv; }
        }
        #pragma unroll
        for (int jh = 0; jh < 2; ++jh) {
            #pragma unroll
            for (int r2 = 0; r2 < 2; ++r2) {
                int jb = jh * 128 + w * 32 + r2 * 16;
                if (jb < NN) {
                    int aoff = (jb + l15) * 224 + ks * 32 + g * 8;
                    s8v a1 = *(const s8v*)(Lh + aoff);
                    s8v a2 = *(const s8v*)(C2h + aoff);
                    #pragma unroll
                    for (int nf = 0; nf < 4; ++nf) {
                        accD[jh][r2][nf] = __builtin_amdgcn_mfma_f32_16x16x32_bf16(
                            a1, b1[nf], accD[jh][r2][nf], 0, 0, 0);
                        accD[jh][r2][nf] = __builtin_amdgcn_mfma_f32_16x16x32_bf16(
                            a2, b2[nf], accD[jh][r2][nf], 0, 0, 0);
                    }
                }
            }
        }
    }

    // ---------- epilogue ----------
    float bv[4];
    #pragma unroll
    for (int nf = 0; nf < 4; ++nf) bv[nf] = bias[nf * 16 + l15];
    float* ob = out + ((size_t)(a0 + al) * NN + (i0 + il)) * 12800;
    #pragma unroll
    for (int jh = 0; jh < 2; ++jh) {
        #pragma unroll
        for (int r2 = 0; r2 < 2; ++r2) {
            int jb = jh * 128 + w * 32 + r2 * 16;
            if (jb < NN) {
                #pragma unroll
                for (int r = 0; r < 4; ++r) {
                    int j = jb + 4 * g + r;
                    if (j < NN) {
                        #pragma unroll
                        for (int nf = 0; nf < 4; ++nf)
                            ob[(size_t)j * 64 + nf * 16 + l15] = accD[jh][r2][nf][r] + bv[nf];
                    }
                }
            }
        }
    }
}

extern "C" void kernel_launch(void* const* d_in, const int* in_sizes, int n_in,
                              void* d_out, int out_size, void* d_ws, size_t ws_size,
                              hipStream_t stream) {
    const float* x    = (const float*)d_in[0];   // [8,200,200,32] fp32
    const float* adj  = (const float*)d_in[1];   // [200,200] fp32
    const float* w    = (const float*)d_in[2];   // [64,288] fp32
    const float* bias = (const float*)d_in[3];   // [64] fp32
    float* out = (float*)d_out;                  // [8,200,200,64] fp32

    char* ws = (char*)d_ws;
    size_t off = 0;
    auto alloc = [&](size_t bytes) { size_t p = off; off = (off + bytes + 255) & ~(size_t)255; return p; };
    float* cs = (float*)(ws + alloc(NN * 4));
    float* rs = (float*)(ws + alloc(NN * 4));
    float* L  = (float*)(ws + alloc(NN * NN * 4));
    unsigned short* Lh   = (unsigned short*)(ws + alloc(224 * 224 * 2));
    unsigned short* C2h  = (unsigned short*)(ws + alloc(224 * 224 * 2));
    unsigned short* LTh  = (unsigned short*)(ws + alloc(256 * 224 * 2));
    unsigned short* C2Th = (unsigned short*)(ws + alloc(256 * 224 * 2));
    unsigned short* WmT  = (unsigned short*)(ws + alloc(192 * 96 * 2));
    size_t fixedEnd = off;

    // chunking over (a, i): per-a Xh+XhT, per-(a,i)-row Y1/Y2
    const int cfgA[8] = {8, 8, 8, 8, 4, 2, 1, 1};
    const int cfgG[8] = {200, 100, 50, 25, 25, 25, 25, 5};
    size_t perA = (size_t)NN * 6400 * 2 + (size_t)6400 * 224 * 2;
    size_t perR = (size_t)2 * 6400 * 2;   // Y1+Y2 bytes per t row
    int Ab = 1, Gi = 5;
    for (int k = 0; k < 8; ++k) {
        size_t R_ = (size_t)cfgA[k] * cfgG[k];
        size_t need = fixedEnd + (size_t)cfgA[k] * perA + R_ * perR + 8192;
        if (need <= ws_size) { Ab = cfgA[k]; Gi = cfgG[k]; break; }
    }
    int R = Ab * Gi;
    unsigned short* Xh  = (unsigned short*)(ws + alloc((size_t)Ab * NN * 6400 * 2));
    unsigned short* XhT = (unsigned short*)(ws + alloc((size_t)Ab * 6400 * 224 * 2));
    unsigned short* Y1  = (unsigned short*)(ws + alloc((size_t)R * 6400 * 2));
    unsigned short* Y2  = (unsigned short*)(ws + alloc((size_t)R * 6400 * 2));

    k_sums<<<dim3(NN), dim3(256), 0, stream>>>(adj, cs, rs);
    k_lap2<<<dim3(224), dim3(256), 0, stream>>>(adj, cs, rs, L, Lh, LTh);
    k_sq2<<<dim3(224), dim3(256), 0, stream>>>(L, C2h, C2Th);
    k_wprep2<<<dim3(72), dim3(256), 0, stream>>>(w, WmT);

    int nIT = (Gi + 31) / 32;
    for (int a0 = 0; a0 < 8; a0 += Ab) {
        k_cast<<<dim3(100, 7, Ab), dim3(256), 0, stream>>>(x, Xh, XhT, a0);
        for (int i0 = 0; i0 < NN; i0 += Gi) {
            k_y<<<dim3(25, nIT, Ab), dim3(256), 0, stream>>>(LTh, C2Th, XhT, Y1, Y2, i0, Gi);
            k_fused<<<dim3(R), dim3(256), 0, stream>>>(Xh, Y1, Y2, WmT, Lh, C2h, bias, out, a0, i0, Gi);
        }
    }
}

// Round 9
// 270.789 us; speedup vs baseline: 1.4781x; 1.1178x over previous
//
#include <hip/hip_runtime.h>

#define NN 200

typedef short s8v __attribute__((ext_vector_type(8)));   // 8 bf16 in 4 VGPRs
typedef float f4v __attribute__((ext_vector_type(4)));   // MFMA accum

__device__ __forceinline__ unsigned short f2bf(float f) {
    unsigned u = __float_as_uint(f);
    u += 0x7fffu + ((u >> 16) & 1u);   // RNE
    return (unsigned short)(u >> 16);
}

// ---------------- prep ----------------
__global__ __launch_bounds__(256) void k_sums(const float* __restrict__ adj,
                                              float* __restrict__ cs, float* __restrict__ rs) {
    int t = blockIdx.x;
    int tid = threadIdx.x;
    float c = 0.f, r = 0.f;
    for (int p = tid; p < NN; p += 256) {
        if (p != t) {
            c += adj[p * NN + t];
            r += adj[t * NN + p];
        }
    }
    #pragma unroll
    for (int off = 32; off; off >>= 1) {
        c += __shfl_down(c, off);
        r += __shfl_down(r, off);
    }
    __shared__ float sc[4], sr[4];
    if ((tid & 63) == 0) { sc[tid >> 6] = c; sr[tid >> 6] = r; }
    __syncthreads();
    if (tid == 0) {
        cs[t] = sc[0] + sc[1] + sc[2] + sc[3];
        rs[t] = sr[0] + sr[1] + sr[2] + sr[3];
    }
}

// L fp32 [200][200]; Lh bf16 [224][224] (row j, col e, zero-padded);
// LTh bf16 [256][224] (row i, col b = L[b][i], zero-padded)
__global__ __launch_bounds__(256) void k_lap2(const float* __restrict__ adj,
    const float* __restrict__ cs, const float* __restrict__ rs,
    float* __restrict__ L, unsigned short* __restrict__ Lh, unsigned short* __restrict__ LTh) {
    int idx = blockIdx.x * 256 + threadIdx.x;
    int p = idx >> 8, q = idx & 255;          // p in [0,224), q in [0,256)
    if (p >= 224) return;
    float v = 0.f;
    if (p < NN && q < NN) {
        float a = (p == q) ? 0.f : adj[p * NN + q];
        float d0 = (cs[p] > 0.f) ? rsqrtf(cs[p]) : 0.f;
        float d1 = (rs[q] > 0.f) ? rsqrtf(rs[q]) : 0.f;
        v = d0 * a * d1;
        L[p * NN + q] = v;
    }
    unsigned short h = f2bf(v);
    if (q < 224) Lh[p * 224 + q] = h;
    LTh[q * 224 + p] = h;
}

// C2 = 2*L*L - I ; C2h [224][224], C2Th [256][224] zero-padded
__global__ __launch_bounds__(256) void k_sq2(const float* __restrict__ L,
    unsigned short* __restrict__ C2h, unsigned short* __restrict__ C2Th) {
    int idx = blockIdx.x * 256 + threadIdx.x;
    int p = idx >> 8, q = idx & 255;
    if (p >= 224) return;
    float v = 0.f;
    if (p < NN && q < NN) {
        float s = 0.f;
        for (int r2 = 0; r2 < NN; ++r2) s += L[p * NN + r2] * L[r2 * NN + q];
        v = 2.f * s - ((p == q) ? 1.f : 0.f);
    }
    unsigned short h = f2bf(v);
    if (q < 224) C2h[p * 224 + q] = h;
    C2Th[q * 224 + p] = h;
}

// WmT bf16 [192 n][96 k], n = k2*64+o, k = k1*32+c  ([n][k]-major for B-frags)
__global__ __launch_bounds__(256) void k_wprep2(const float* __restrict__ w,
    unsigned short* __restrict__ WmT) {
    int idx = blockIdx.x * 256 + threadIdx.x;
    if (idx < 192 * 96) {
        int n = idx / 96, k = idx - n * 96;
        int k1 = k >> 5, c = k & 31;
        int k2 = n >> 6, o = n & 63;
        WmT[idx] = f2bf(w[o * 288 + (k1 * 3 + k2) * 32 + c]);
    }
}

// ---------------- cast: X -> Xh bf16 [a][b][6400], XhT bf16 [a][6400][224] (b padded 0) --
__global__ __launch_bounds__(256) void k_cast(const float* __restrict__ x,
    unsigned short* __restrict__ Xh, unsigned short* __restrict__ XhT, int a0) {
    int a = blockIdx.z;
    int b0 = blockIdx.y * 32;
    int jc0 = blockIdx.x * 64;
    int tid = threadIdx.x;
    __shared__ unsigned short Xs[32][65];
    const float* xb = x + (size_t)(a0 + a) * (NN * 6400);
    int r = tid >> 6, q = tid & 63;
    #pragma unroll
    for (int k = 0; k < 8; ++k) {
        int rr = r + k * 4;
        int b = b0 + rr;
        float v = (b < NN) ? xb[(size_t)b * 6400 + jc0 + q] : 0.f;
        unsigned short h = f2bf(v);
        Xs[rr][q] = h;
        if (b < NN) Xh[((size_t)a * NN + b) * 6400 + jc0 + q] = h;
    }
    __syncthreads();
    int jcl = tid >> 2, bs = (tid & 3) * 8;
    s8v v;
    #pragma unroll
    for (int j2 = 0; j2 < 8; ++j2) v[j2] = (short)Xs[bs + j2][jcl];
    *(s8v*)(XhT + (size_t)a * (6400 * 224) + (size_t)(jc0 + jcl) * 224 + b0 + bs) = v;
}

// ---------------- stage 1: Y1[i][jc] = sum_b L[b][i] X[b][jc]; Y2 with C2. MFMA. --------
__global__ __launch_bounds__(256) void k_y(
    const unsigned short* __restrict__ LTh, const unsigned short* __restrict__ C2Th,
    const unsigned short* __restrict__ XhT,
    unsigned short* __restrict__ Y1, unsigned short* __restrict__ Y2, int i0, int Gi) {
    int a = blockIdx.z;
    int itile = blockIdx.y;
    int jc0 = blockIdx.x << 8;
    int tid = threadIdx.x;
    int w = tid >> 6, l15 = tid & 15, g = (tid & 63) >> 4;

    __shared__ unsigned short As[2][32][40];   // 80B rows: 16B-aligned b128 frags
    __shared__ unsigned short Xt[256][40];     // [jc][b]  ([n][k]-major)

    const unsigned short* xtb = XhT + (size_t)a * (6400 * 224) + (size_t)jc0 * 224;
    int ibase = i0 + itile * 32;

    f4v z = {0.f, 0.f, 0.f, 0.f};
    f4v acc[2][2][4];
    #pragma unroll
    for (int m = 0; m < 2; ++m)
        #pragma unroll
        for (int f = 0; f < 2; ++f)
            #pragma unroll
            for (int n = 0; n < 4; ++n) acc[m][f][n] = z;

    int amat = tid >> 7, arr = (tid >> 2) & 31, ah = tid & 3;
    const unsigned short* asrc = (amat ? C2Th : LTh) + (size_t)(ibase + arr) * 224 + ah * 8;

    for (int ks = 0; ks < 7; ++ks) {
        int b0 = ks * 32;
        __syncthreads();
        *(s8v*)&As[amat][arr][ah * 8] = *(const s8v*)(asrc + b0);
        const unsigned short* xs = xtb + (size_t)tid * 224 + b0;
        #pragma unroll
        for (int h = 0; h < 4; ++h)
            *(s8v*)&Xt[tid][h * 8] = *(const s8v*)(xs + h * 8);
        __syncthreads();

        s8v bfr[4];
        #pragma unroll
        for (int nf = 0; nf < 4; ++nf)
            bfr[nf] = *(s8v*)&Xt[w * 64 + nf * 16 + l15][g * 8];
        #pragma unroll
        for (int m = 0; m < 2; ++m) {
            #pragma unroll
            for (int f = 0; f < 2; ++f) {
                s8v af = *(s8v*)&As[m][f * 16 + l15][g * 8];
                #pragma unroll
                for (int nf = 0; nf < 4; ++nf)
                    acc[m][f][nf] = __builtin_amdgcn_mfma_f32_16x16x32_bf16(
                        af, bfr[nf], acc[m][f][nf], 0, 0, 0);
            }
        }
    }

    #pragma unroll
    for (int f = 0; f < 2; ++f) {
        #pragma unroll
        for (int r = 0; r < 4; ++r) {
            int il_ = itile * 32 + f * 16 + 4 * g + r;
            if (il_ < Gi && i0 + il_ < NN) {
                size_t base = ((size_t)a * Gi + il_) * 6400 + jc0 + w * 64 + l15;
                #pragma unroll
                for (int nf = 0; nf < 4; ++nf) {
                    Y1[base + nf * 16] = f2bf(acc[0][f][nf][r]);
                    Y2[base + nf * 16] = f2bf(acc[1][f][nf][r]);
                }
            }
        }
    }
}

// ---------------- fused stages 2+3: one block per t row, 256 threads / 4 waves.
// Quarter-major, low-register: each wave owns 4x 16-row quarters.
// Phase A (E only): accE[8] per quarter -> LDS [e/8][o][e%8].
// Phase B (per quarter): accD[4] = U x W_D (12 MFMA) + sum_e L*E1 + C2*E2, store+bias.
// MFMA count/order per output element identical to r4/r8 -> bit-identical results.
// Peak live regs ~phase B (~100-120 incl acc) -> 3 waves/SIMD; LDS 51200 -> 3 blocks/CU.
// NO min-waves bound (forcing it spills: r6/r7 post-mortem).
__global__ __launch_bounds__(256) void k_fused(
    const unsigned short* __restrict__ Xh, const unsigned short* __restrict__ Y1,
    const unsigned short* __restrict__ Y2, const unsigned short* __restrict__ WmT,
    const unsigned short* __restrict__ Lh, const unsigned short* __restrict__ C2h,
    const float* __restrict__ bias, float* __restrict__ out,
    int a0, int i0, int Gi) {
    int tl = blockIdx.x;
    int al = tl / Gi, il = tl - al * Gi;
    int tid = threadIdx.x;
    int w = tid >> 6, l15 = tid & 15, g = (tid & 63) >> 4;

    // E LDS: [tensor][e/8][o][e%8], e < 200 (25 subtiles); read bank = (4*l15+d)%32 -> 2-way
    __shared__ unsigned short EL[2][25][64][8];   // 51200 B

    const unsigned short* xrow = Xh + (size_t)(al * NN + i0 + il) * 6400;
    const unsigned short* y1r = Y1 + (size_t)tl * 6400;
    const unsigned short* y2r = Y2 + (size_t)tl * 6400;

    f4v z = {0.f, 0.f, 0.f, 0.f};

    // ---------- phase A: E fragments only ----------
    #pragma unroll
    for (int q = 0; q < 4; ++q) {
        int jrow0 = (q >> 1) * 128 + w * 32 + (q & 1) * 16;
        if (jrow0 >= NN) continue;               // wave-uniform skip (rows 208/224/240)
        int j = jrow0 + l15;
        int jc = j < NN ? j : NN - 1;
        s8v ax = *(const s8v*)(xrow + jc * 32 + g * 8);
        s8v ay1 = *(const s8v*)(y1r + jc * 32 + g * 8);
        s8v ay2 = *(const s8v*)(y2r + jc * 32 + g * 8);

        f4v accE[8];
        #pragma unroll
        for (int n = 0; n < 8; ++n) accE[n] = z;

        #pragma unroll
        for (int s = 0; s < 3; ++s) {
            s8v af = (s == 0) ? ax : ((s == 1) ? ay1 : ay2);
            #pragma unroll
            for (int k = 0; k < 8; ++k) {
                s8v bf = *(const s8v*)(WmT + ((k + 4) * 16 + l15) * 96 + s * 32 + g * 8);
                accE[k] = __builtin_amdgcn_mfma_f32_16x16x32_bf16(af, bf, accE[k], 0, 0, 0);
            }
        }

        #pragma unroll
        for (int k = 0; k < 8; ++k) {
            int tns = k >> 2;
            int o = (k & 3) * 16 + l15;
            #pragma unroll
            for (int r0 = 0; r0 < 4; r0 += 2) {
                int e = jrow0 + 4 * g + r0;
                if (e < NN) {
                    unsigned pk = (unsigned)f2bf(accE[k][r0]) |
                                  ((unsigned)f2bf(accE[k][r0 + 1]) << 16);
                    *(unsigned*)&EL[tns][e >> 3][o][e & 7] = pk;
                }
            }
        }
    }

    __syncthreads();

    float bv[4];
    #pragma unroll
    for (int nf = 0; nf < 4; ++nf) bv[nf] = bias[nf * 16 + l15];
    float* ob = out + ((size_t)(a0 + al) * NN + (i0 + il)) * 12800;

    // ---------- phase B: D + L*E1 + C2*E2, one quarter at a time ----------
    #pragma unroll
    for (int q = 0; q < 4; ++q) {
        int jrow0 = (q >> 1) * 128 + w * 32 + (q & 1) * 16;
        if (jrow0 >= NN) continue;
        int j = jrow0 + l15;
        int jc = j < NN ? j : NN - 1;
        s8v ax = *(const s8v*)(xrow + jc * 32 + g * 8);
        s8v ay1 = *(const s8v*)(y1r + jc * 32 + g * 8);
        s8v ay2 = *(const s8v*)(y2r + jc * 32 + g * 8);

        f4v accD[4];
        #pragma unroll
        for (int n = 0; n < 4; ++n) accD[n] = z;

        // D part (same MFMA order as before: s = 0,1,2)
        #pragma unroll
        for (int s = 0; s < 3; ++s) {
            s8v af = (s == 0) ? ax : ((s == 1) ? ay1 : ay2);
            #pragma unroll
            for (int nf = 0; nf < 4; ++nf) {
                s8v bf = *(const s8v*)(WmT + (nf * 16 + l15) * 96 + s * 32 + g * 8);
                accD[nf] = __builtin_amdgcn_mfma_f32_16x16x32_bf16(af, bf, accD[nf], 0, 0, 0);
            }
        }

        // L*E1 + C2*E2 part
        #pragma unroll
        for (int ks = 0; ks < 7; ++ks) {
            int eb = 4 * ks + g;
            s8v b1[4], b2[4];
            if (eb < 25) {
                #pragma unroll
                for (int nf = 0; nf < 4; ++nf) {
                    b1[nf] = *(const s8v*)&EL[0][eb][nf * 16 + l15][0];
                    b2[nf] = *(const s8v*)&EL[1][eb][nf * 16 + l15][0];
                }
            } else {
                s8v zv = {0, 0, 0, 0, 0, 0, 0, 0};
                #pragma unroll
                for (int nf = 0; nf < 4; ++nf) { b1[nf] = zv; b2[nf] = zv; }
            }
            int aoff = (jrow0 + l15) * 224 + ks * 32 + g * 8;
            s8v a1 = *(const s8v*)(Lh + aoff);
            s8v a2 = *(const s8v*)(C2h + aoff);
            #pragma unroll
            for (int nf = 0; nf < 4; ++nf) {
                accD[nf] = __builtin_amdgcn_mfma_f32_16x16x32_bf16(a1, b1[nf], accD[nf], 0, 0, 0);
                accD[nf] = __builtin_amdgcn_mfma_f32_16x16x32_bf16(a2, b2[nf], accD[nf], 0, 0, 0);
            }
        }

        // store this quarter
        #pragma unroll
        for (int r = 0; r < 4; ++r) {
            int jj = jrow0 + 4 * g + r;
            if (jj < NN) {
                #pragma unroll
                for (int nf = 0; nf < 4; ++nf)
                    ob[(size_t)jj * 64 + nf * 16 + l15] = accD[nf][r] + bv[nf];
            }
        }
    }
}

extern "C" void kernel_launch(void* const* d_in, const int* in_sizes, int n_in,
                              void* d_out, int out_size, void* d_ws, size_t ws_size,
                              hipStream_t stream) {
    const float* x    = (const float*)d_in[0];   // [8,200,200,32] fp32
    const float* adj  = (const float*)d_in[1];   // [200,200] fp32
    const float* w    = (const float*)d_in[2];   // [64,288] fp32
    const float* bias = (const float*)d_in[3];   // [64] fp32
    float* out = (float*)d_out;                  // [8,200,200,64] fp32

    char* ws = (char*)d_ws;
    size_t off = 0;
    auto alloc = [&](size_t bytes) { size_t p = off; off = (off + bytes + 255) & ~(size_t)255; return p; };
    float* cs = (float*)(ws + alloc(NN * 4));
    float* rs = (float*)(ws + alloc(NN * 4));
    float* L  = (float*)(ws + alloc(NN * NN * 4));
    unsigned short* Lh   = (unsigned short*)(ws + alloc(224 * 224 * 2));
    unsigned short* C2h  = (unsigned short*)(ws + alloc(224 * 224 * 2));
    unsigned short* LTh  = (unsigned short*)(ws + alloc(256 * 224 * 2));
    unsigned short* C2Th = (unsigned short*)(ws + alloc(256 * 224 * 2));
    unsigned short* WmT  = (unsigned short*)(ws + alloc(192 * 96 * 2));
    size_t fixedEnd = off;

    // chunking over (a, i): per-a Xh+XhT, per-(a,i)-row Y1/Y2
    const int cfgA[8] = {8, 8, 8, 8, 4, 2, 1, 1};
    const int cfgG[8] = {200, 100, 50, 25, 25, 25, 25, 5};
    size_t perA = (size_t)NN * 6400 * 2 + (size_t)6400 * 224 * 2;
    size_t perR = (size_t)2 * 6400 * 2;   // Y1+Y2 bytes per t row
    int Ab = 1, Gi = 5;
    for (int k = 0; k < 8; ++k) {
        size_t R_ = (size_t)cfgA[k] * cfgG[k];
        size_t need = fixedEnd + (size_t)cfgA[k] * perA + R_ * perR + 8192;
        if (need <= ws_size) { Ab = cfgA[k]; Gi = cfgG[k]; break; }
    }
    int R = Ab * Gi;
    unsigned short* Xh  = (unsigned short*)(ws + alloc((size_t)Ab * NN * 6400 * 2));
    unsigned short* XhT = (unsigned short*)(ws + alloc((size_t)Ab * 6400 * 224 * 2));
    unsigned short* Y1  = (unsigned short*)(ws + alloc((size_t)R * 6400 * 2));
    unsigned short* Y2  = (unsigned short*)(ws + alloc((size_t)R * 6400 * 2));

    k_sums<<<dim3(NN), dim3(256), 0, stream>>>(adj, cs, rs);
    k_lap2<<<dim3(224), dim3(256), 0, stream>>>(adj, cs, rs, L, Lh, LTh);
    k_sq2<<<dim3(224), dim3(256), 0, stream>>>(L, C2h, C2Th);
    k_wprep2<<<dim3(72), dim3(256), 0, stream>>>(w, WmT);

    int nIT = (Gi + 31) / 32;
    for (int a0 = 0; a0 < 8; a0 += Ab) {
        k_cast<<<dim3(100, 7, Ab), dim3(256), 0, stream>>>(x, Xh, XhT, a0);
        for (int i0 = 0; i0 < NN; i0 += Gi) {
            k_y<<<dim3(25, nIT, Ab), dim3(256), 0, stream>>>(LTh, C2Th, XhT, Y1, Y2, i0, Gi);
            k_fused<<<dim3(R), dim3(256), 0, stream>>>(Xh, Y1, Y2, WmT, Lh, C2h, bias, out, a0, i0, Gi);
        }
    }
}

// Round 10
// 260.552 us; speedup vs baseline: 1.5362x; 1.0393x over previous
//
#include <hip/hip_runtime.h>

#define NN 200

typedef short s8v __attribute__((ext_vector_type(8)));   // 8 bf16 in 4 VGPRs
typedef float f4v __attribute__((ext_vector_type(4)));   // MFMA accum

__device__ __forceinline__ unsigned short f2bf(float f) {
    unsigned u = __float_as_uint(f);
    u += 0x7fffu + ((u >> 16) & 1u);   // RNE
    return (unsigned short)(u >> 16);
}

// ---------------- prep ----------------
__global__ __launch_bounds__(256) void k_sums(const float* __restrict__ adj,
                                              float* __restrict__ cs, float* __restrict__ rs) {
    int t = blockIdx.x;
    int tid = threadIdx.x;
    float c = 0.f, r = 0.f;
    for (int p = tid; p < NN; p += 256) {
        if (p != t) {
            c += adj[p * NN + t];
            r += adj[t * NN + p];
        }
    }
    #pragma unroll
    for (int off = 32; off; off >>= 1) {
        c += __shfl_down(c, off);
        r += __shfl_down(r, off);
    }
    __shared__ float sc[4], sr[4];
    if ((tid & 63) == 0) { sc[tid >> 6] = c; sr[tid >> 6] = r; }
    __syncthreads();
    if (tid == 0) {
        cs[t] = sc[0] + sc[1] + sc[2] + sc[3];
        rs[t] = sr[0] + sr[1] + sr[2] + sr[3];
    }
}

// L fp32 [200][200]; Lh bf16 [224][224] (row j, col e, zero-padded);
// LTh bf16 [256][224] (row i, col b = L[b][i], zero-padded)
__global__ __launch_bounds__(256) void k_lap2(const float* __restrict__ adj,
    const float* __restrict__ cs, const float* __restrict__ rs,
    float* __restrict__ L, unsigned short* __restrict__ Lh, unsigned short* __restrict__ LTh) {
    int idx = blockIdx.x * 256 + threadIdx.x;
    int p = idx >> 8, q = idx & 255;          // p in [0,224), q in [0,256)
    if (p >= 224) return;
    float v = 0.f;
    if (p < NN && q < NN) {
        float a = (p == q) ? 0.f : adj[p * NN + q];
        float d0 = (cs[p] > 0.f) ? rsqrtf(cs[p]) : 0.f;
        float d1 = (rs[q] > 0.f) ? rsqrtf(rs[q]) : 0.f;
        v = d0 * a * d1;
        L[p * NN + q] = v;
    }
    unsigned short h = f2bf(v);
    if (q < 224) Lh[p * 224 + q] = h;
    LTh[q * 224 + p] = h;
}

// C2 = 2*L*L - I ; C2h [224][224], C2Th [256][224] zero-padded
__global__ __launch_bounds__(256) void k_sq2(const float* __restrict__ L,
    unsigned short* __restrict__ C2h, unsigned short* __restrict__ C2Th) {
    int idx = blockIdx.x * 256 + threadIdx.x;
    int p = idx >> 8, q = idx & 255;
    if (p >= 224) return;
    float v = 0.f;
    if (p < NN && q < NN) {
        float s = 0.f;
        for (int r2 = 0; r2 < NN; ++r2) s += L[p * NN + r2] * L[r2 * NN + q];
        v = 2.f * s - ((p == q) ? 1.f : 0.f);
    }
    unsigned short h = f2bf(v);
    if (q < 224) C2h[p * 224 + q] = h;
    C2Th[q * 224 + p] = h;
}

// WmT bf16 [192 n][96 k], n = k2*64+o, k = k1*32+c  ([n][k]-major for B-frags)
__global__ __launch_bounds__(256) void k_wprep2(const float* __restrict__ w,
    unsigned short* __restrict__ WmT) {
    int idx = blockIdx.x * 256 + threadIdx.x;
    if (idx < 192 * 96) {
        int n = idx / 96, k = idx - n * 96;
        int k1 = k >> 5, c = k & 31;
        int k2 = n >> 6, o = n & 63;
        WmT[idx] = f2bf(w[o * 288 + (k1 * 3 + k2) * 32 + c]);
    }
}

// ---------------- cast: X -> Xh bf16 [a][b][6400], XhT bf16 [a][6400][224] (b padded 0) --
__global__ __launch_bounds__(256) void k_cast(const float* __restrict__ x,
    unsigned short* __restrict__ Xh, unsigned short* __restrict__ XhT, int a0) {
    int a = blockIdx.z;
    int b0 = blockIdx.y * 32;
    int jc0 = blockIdx.x * 64;
    int tid = threadIdx.x;
    __shared__ unsigned short Xs[32][65];
    const float* xb = x + (size_t)(a0 + a) * (NN * 6400);
    int r = tid >> 6, q = tid & 63;
    #pragma unroll
    for (int k = 0; k < 8; ++k) {
        int rr = r + k * 4;
        int b = b0 + rr;
        float v = (b < NN) ? xb[(size_t)b * 6400 + jc0 + q] : 0.f;
        unsigned short h = f2bf(v);
        Xs[rr][q] = h;
        if (b < NN) Xh[((size_t)a * NN + b) * 6400 + jc0 + q] = h;
    }
    __syncthreads();
    int jcl = tid >> 2, bs = (tid & 3) * 8;
    s8v v;
    #pragma unroll
    for (int j2 = 0; j2 < 8; ++j2) v[j2] = (short)Xs[bs + j2][jcl];
    *(s8v*)(XhT + (size_t)a * (6400 * 224) + (size_t)(jc0 + jcl) * 224 + b0 + bs) = v;
}

// ---------------- stage 1: Y1[i][jc] = sum_b L[b][i] X[b][jc]; Y2 with C2. MFMA. --------
__global__ __launch_bounds__(256) void k_y(
    const unsigned short* __restrict__ LTh, const unsigned short* __restrict__ C2Th,
    const unsigned short* __restrict__ XhT,
    unsigned short* __restrict__ Y1, unsigned short* __restrict__ Y2, int i0, int Gi) {
    int a = blockIdx.z;
    int itile = blockIdx.y;
    int jc0 = blockIdx.x << 8;
    int tid = threadIdx.x;
    int w = tid >> 6, l15 = tid & 15, g = (tid & 63) >> 4;

    __shared__ unsigned short As[2][32][40];   // 80B rows: 16B-aligned b128 frags
    __shared__ unsigned short Xt[256][40];     // [jc][b]  ([n][k]-major)

    const unsigned short* xtb = XhT + (size_t)a * (6400 * 224) + (size_t)jc0 * 224;
    int ibase = i0 + itile * 32;

    f4v z = {0.f, 0.f, 0.f, 0.f};
    f4v acc[2][2][4];
    #pragma unroll
    for (int m = 0; m < 2; ++m)
        #pragma unroll
        for (int f = 0; f < 2; ++f)
            #pragma unroll
            for (int n = 0; n < 4; ++n) acc[m][f][n] = z;

    int amat = tid >> 7, arr = (tid >> 2) & 31, ah = tid & 3;
    const unsigned short* asrc = (amat ? C2Th : LTh) + (size_t)(ibase + arr) * 224 + ah * 8;

    for (int ks = 0; ks < 7; ++ks) {
        int b0 = ks * 32;
        __syncthreads();
        *(s8v*)&As[amat][arr][ah * 8] = *(const s8v*)(asrc + b0);
        const unsigned short* xs = xtb + (size_t)tid * 224 + b0;
        #pragma unroll
        for (int h = 0; h < 4; ++h)
            *(s8v*)&Xt[tid][h * 8] = *(const s8v*)(xs + h * 8);
        __syncthreads();

        s8v bfr[4];
        #pragma unroll
        for (int nf = 0; nf < 4; ++nf)
            bfr[nf] = *(s8v*)&Xt[w * 64 + nf * 16 + l15][g * 8];
        #pragma unroll
        for (int m = 0; m < 2; ++m) {
            #pragma unroll
            for (int f = 0; f < 2; ++f) {
                s8v af = *(s8v*)&As[m][f * 16 + l15][g * 8];
                #pragma unroll
                for (int nf = 0; nf < 4; ++nf)
                    acc[m][f][nf] = __builtin_amdgcn_mfma_f32_16x16x32_bf16(
                        af, bfr[nf], acc[m][f][nf], 0, 0, 0);
            }
        }
    }

    #pragma unroll
    for (int f = 0; f < 2; ++f) {
        #pragma unroll
        for (int r = 0; r < 4; ++r) {
            int il_ = itile * 32 + f * 16 + 4 * g + r;
            if (il_ < Gi && i0 + il_ < NN) {
                size_t base = ((size_t)a * Gi + il_) * 6400 + jc0 + w * 64 + l15;
                #pragma unroll
                for (int nf = 0; nf < 4; ++nf) {
                    Y1[base + nf * 16] = f2bf(acc[0][f][nf][r]);
                    Y2[base + nf * 16] = f2bf(acc[1][f][nf][r]);
                }
            }
        }
    }
}

// ---------------- fused stages 2+3: one block per t row, 512 threads / 8 waves.
// Each wave owns 2x 16-row quarters: jrow0 = wv*16 + q*128 (13 active of 16).
// Phase A (E only): accE[8] per quarter -> LDS [e/8][o][e%8].
// Phase B (per quarter): accD[4] = U x W_D (12 MFMA) + sum_e L*E1 + C2*E2, store+bias.
// Per-thread structure/registers identical to r9 (76 VGPR) -> no spill; LDS 51200 ->
// 3 blocks/CU x 8 waves = up to 24 waves/CU. NO min-waves bound (r6/r7: forcing spills).
__global__ __launch_bounds__(512) void k_fused(
    const unsigned short* __restrict__ Xh, const unsigned short* __restrict__ Y1,
    const unsigned short* __restrict__ Y2, const unsigned short* __restrict__ WmT,
    const unsigned short* __restrict__ Lh, const unsigned short* __restrict__ C2h,
    const float* __restrict__ bias, float* __restrict__ out,
    int a0, int i0, int Gi) {
    int tl = blockIdx.x;
    int al = tl / Gi, il = tl - al * Gi;
    int tid = threadIdx.x;
    int wv = tid >> 6, l15 = tid & 15, g = (tid & 63) >> 4;

    // E LDS: [tensor][e/8][o][e%8], e < 200 (25 subtiles); read bank = (4*l15+d)%32 -> 2-way
    __shared__ unsigned short EL[2][25][64][8];   // 51200 B

    const unsigned short* xrow = Xh + (size_t)(al * NN + i0 + il) * 6400;
    const unsigned short* y1r = Y1 + (size_t)tl * 6400;
    const unsigned short* y2r = Y2 + (size_t)tl * 6400;

    f4v z = {0.f, 0.f, 0.f, 0.f};

    // ---------- phase A: E fragments only ----------
    #pragma unroll
    for (int q = 0; q < 2; ++q) {
        int jrow0 = wv * 16 + q * 128;
        if (jrow0 >= NN) continue;               // wave-uniform skip (rows 208/224/240)
        int j = jrow0 + l15;
        int jc = j < NN ? j : NN - 1;
        s8v ax = *(const s8v*)(xrow + jc * 32 + g * 8);
        s8v ay1 = *(const s8v*)(y1r + jc * 32 + g * 8);
        s8v ay2 = *(const s8v*)(y2r + jc * 32 + g * 8);

        f4v accE[8];
        #pragma unroll
        for (int n = 0; n < 8; ++n) accE[n] = z;

        #pragma unroll
        for (int s = 0; s < 3; ++s) {
            s8v af = (s == 0) ? ax : ((s == 1) ? ay1 : ay2);
            #pragma unroll
            for (int k = 0; k < 8; ++k) {
                s8v bf = *(const s8v*)(WmT + ((k + 4) * 16 + l15) * 96 + s * 32 + g * 8);
                accE[k] = __builtin_amdgcn_mfma_f32_16x16x32_bf16(af, bf, accE[k], 0, 0, 0);
            }
        }

        #pragma unroll
        for (int k = 0; k < 8; ++k) {
            int tns = k >> 2;
            int o = (k & 3) * 16 + l15;
            #pragma unroll
            for (int r0 = 0; r0 < 4; r0 += 2) {
                int e = jrow0 + 4 * g + r0;
                if (e < NN) {
                    unsigned pk = (unsigned)f2bf(accE[k][r0]) |
                                  ((unsigned)f2bf(accE[k][r0 + 1]) << 16);
                    *(unsigned*)&EL[tns][e >> 3][o][e & 7] = pk;
                }
            }
        }
    }

    __syncthreads();

    float bv[4];
    #pragma unroll
    for (int nf = 0; nf < 4; ++nf) bv[nf] = bias[nf * 16 + l15];
    float* ob = out + ((size_t)(a0 + al) * NN + (i0 + il)) * 12800;

    // ---------- phase B: D + L*E1 + C2*E2, one quarter at a time ----------
    #pragma unroll
    for (int q = 0; q < 2; ++q) {
        int jrow0 = wv * 16 + q * 128;
        if (jrow0 >= NN) continue;
        int j = jrow0 + l15;
        int jc = j < NN ? j : NN - 1;
        s8v ax = *(const s8v*)(xrow + jc * 32 + g * 8);
        s8v ay1 = *(const s8v*)(y1r + jc * 32 + g * 8);
        s8v ay2 = *(const s8v*)(y2r + jc * 32 + g * 8);

        f4v accD[4];
        #pragma unroll
        for (int n = 0; n < 4; ++n) accD[n] = z;

        // D part (same MFMA order as before: s = 0,1,2)
        #pragma unroll
        for (int s = 0; s < 3; ++s) {
            s8v af = (s == 0) ? ax : ((s == 1) ? ay1 : ay2);
            #pragma unroll
            for (int nf = 0; nf < 4; ++nf) {
                s8v bf = *(const s8v*)(WmT + (nf * 16 + l15) * 96 + s * 32 + g * 8);
                accD[nf] = __builtin_amdgcn_mfma_f32_16x16x32_bf16(af, bf, accD[nf], 0, 0, 0);
            }
        }

        // L*E1 + C2*E2 part
        #pragma unroll
        for (int ks = 0; ks < 7; ++ks) {
            int eb = 4 * ks + g;
            s8v b1[4], b2[4];
            if (eb < 25) {
                #pragma unroll
                for (int nf = 0; nf < 4; ++nf) {
                    b1[nf] = *(const s8v*)&EL[0][eb][nf * 16 + l15][0];
                    b2[nf] = *(const s8v*)&EL[1][eb][nf * 16 + l15][0];
                }
            } else {
                s8v zv = {0, 0, 0, 0, 0, 0, 0, 0};
                #pragma unroll
                for (int nf = 0; nf < 4; ++nf) { b1[nf] = zv; b2[nf] = zv; }
            }
            int aoff = (jrow0 + l15) * 224 + ks * 32 + g * 8;
            s8v a1 = *(const s8v*)(Lh + aoff);
            s8v a2 = *(const s8v*)(C2h + aoff);
            #pragma unroll
            for (int nf = 0; nf < 4; ++nf) {
                accD[nf] = __builtin_amdgcn_mfma_f32_16x16x32_bf16(a1, b1[nf], accD[nf], 0, 0, 0);
                accD[nf] = __builtin_amdgcn_mfma_f32_16x16x32_bf16(a2, b2[nf], accD[nf], 0, 0, 0);
            }
        }

        // store this quarter
        #pragma unroll
        for (int r = 0; r < 4; ++r) {
            int jj = jrow0 + 4 * g + r;
            if (jj < NN) {
                #pragma unroll
                for (int nf = 0; nf < 4; ++nf)
                    ob[(size_t)jj * 64 + nf * 16 + l15] = accD[nf][r] + bv[nf];
            }
        }
    }
}

extern "C" void kernel_launch(void* const* d_in, const int* in_sizes, int n_in,
                              void* d_out, int out_size, void* d_ws, size_t ws_size,
                              hipStream_t stream) {
    const float* x    = (const float*)d_in[0];   // [8,200,200,32] fp32
    const float* adj  = (const float*)d_in[1];   // [200,200] fp32
    const float* w    = (const float*)d_in[2];   // [64,288] fp32
    const float* bias = (const float*)d_in[3];   // [64] fp32
    float* out = (float*)d_out;                  // [8,200,200,64] fp32

    char* ws = (char*)d_ws;
    size_t off = 0;
    auto alloc = [&](size_t bytes) { size_t p = off; off = (off + bytes + 255) & ~(size_t)255; return p; };
    float* cs = (float*)(ws + alloc(NN * 4));
    float* rs = (float*)(ws + alloc(NN * 4));
    float* L  = (float*)(ws + alloc(NN * NN * 4));
    unsigned short* Lh   = (unsigned short*)(ws + alloc(224 * 224 * 2));
    unsigned short* C2h  = (unsigned short*)(ws + alloc(224 * 224 * 2));
    unsigned short* LTh  = (unsigned short*)(ws + alloc(256 * 224 * 2));
    unsigned short* C2Th = (unsigned short*)(ws + alloc(256 * 224 * 2));
    unsigned short* WmT  = (unsigned short*)(ws + alloc(192 * 96 * 2));
    size_t fixedEnd = off;

    // chunking over (a, i): per-a Xh+XhT, per-(a,i)-row Y1/Y2
    const int cfgA[8] = {8, 8, 8, 8, 4, 2, 1, 1};
    const int cfgG[8] = {200, 100, 50, 25, 25, 25, 25, 5};
    size_t perA = (size_t)NN * 6400 * 2 + (size_t)6400 * 224 * 2;
    size_t perR = (size_t)2 * 6400 * 2;   // Y1+Y2 bytes per t row
    int Ab = 1, Gi = 5;
    for (int k = 0; k < 8; ++k) {
        size_t R_ = (size_t)cfgA[k] * cfgG[k];
        size_t need = fixedEnd + (size_t)cfgA[k] * perA + R_ * perR + 8192;
        if (need <= ws_size) { Ab = cfgA[k]; Gi = cfgG[k]; break; }
    }
    int R = Ab * Gi;
    unsigned short* Xh  = (unsigned short*)(ws + alloc((size_t)Ab * NN * 6400 * 2));
    unsigned short* XhT = (unsigned short*)(ws + alloc((size_t)Ab * 6400 * 224 * 2));
    unsigned short* Y1  = (unsigned short*)(ws + alloc((size_t)R * 6400 * 2));
    unsigned short* Y2  = (unsigned short*)(ws + alloc((size_t)R * 6400 * 2));

    k_sums<<<dim3(NN), dim3(256), 0, stream>>>(adj, cs, rs);
    k_lap2<<<dim3(224), dim3(256), 0, stream>>>(adj, cs, rs, L, Lh, LTh);
    k_sq2<<<dim3(224), dim3(256), 0, stream>>>(L, C2h, C2Th);
    k_wprep2<<<dim3(72), dim3(256), 0, stream>>>(w, WmT);

    int nIT = (Gi + 31) / 32;
    for (int a0 = 0; a0 < 8; a0 += Ab) {
        k_cast<<<dim3(100, 7, Ab), dim3(256), 0, stream>>>(x, Xh, XhT, a0);
        for (int i0 = 0; i0 < NN; i0 += Gi) {
            k_y<<<dim3(25, nIT, Ab), dim3(256), 0, stream>>>(LTh, C2Th, XhT, Y1, Y2, i0, Gi);
            k_fused<<<dim3(R), dim3(512), 0, stream>>>(Xh, Y1, Y2, WmT, Lh, C2h, bias, out, a0, i0, Gi);
        }
    }
}